// Round 10
// baseline (528.853 us; speedup 1.0000x reference)
//
#include <hip/hip_runtime.h>
#include <hip/hip_fp16.h>

#define N_NODES 100000
#define N_EDGES 1600000
#define K_ITER 10

#define TPN 6    // threads per node; lane owns 8 feats (16 B fp16 gather)
#define NPB 32   // nodes per block (192 threads = 3 waves)
#define PAD 8    // row length padded to multiple of 8 (zero-edges)
#define CSTRIDE 8 // counter spread: one u32 per 32 B sector

#define SCAN_TB   256
#define SCAN_EPT  8
#define SCAN_SEG  (SCAN_TB * SCAN_EPT)
#define SCAN_NB   ((N_NODES + SCAN_SEG - 1) / SCAN_SEG)   // 49

typedef unsigned int u32;
typedef u32   u32x4 __attribute__((ext_vector_type(4)));
typedef float f32x4 __attribute__((ext_vector_type(4)));

// ---------------------------------------------------------------------------
// Spread counters: cnt[r*8] — one counter per 32B sector so memory-side
// atomic serialization is 16 deep (1.6M/100k sectors), not 256 deep.
__global__ void k_count(const int* __restrict__ row, u32* __restrict__ cnt,
                        unsigned char* __restrict__ pos_local, int E) {
    int i = blockIdx.x * blockDim.x + threadIdx.x;
    if (i < E) pos_local[i] = (unsigned char)atomicAdd(&cnt[row[i] << 3], 1u);
}

__device__ __forceinline__ int padded_cnt(const u32* cnt, int i) {
    int cv = (int)cnt[i << 3];
    return (cv + (PAD - 1)) & ~(PAD - 1);
}

__global__ void k_scanA(const u32* __restrict__ cnt, int* __restrict__ thread_off,
                        int* __restrict__ blocksum) {
    __shared__ int sh[SCAN_TB];
    int b = blockIdx.x, t = threadIdx.x;
    int base = b * SCAN_SEG + t * SCAN_EPT;
    int s = 0;
#pragma unroll
    for (int j = 0; j < SCAN_EPT; ++j) {
        int i = base + j;
        if (i < N_NODES) s += padded_cnt(cnt, i);
    }
    sh[t] = s;
    __syncthreads();
    for (int off = 1; off < SCAN_TB; off <<= 1) {
        int v = (t >= off) ? sh[t - off] : 0;
        __syncthreads();
        sh[t] += v;
        __syncthreads();
    }
    thread_off[b * SCAN_TB + t] = sh[t] - s;
    if (t == SCAN_TB - 1) blocksum[b] = sh[t];
}

__global__ void k_scanB(const int* __restrict__ blocksum, int* __restrict__ blockoff,
                        int* __restrict__ rowptr) {
    __shared__ int sh[SCAN_TB];
    int t = threadIdx.x;
    int v = (t < SCAN_NB) ? blocksum[t] : 0;
    sh[t] = v;
    __syncthreads();
    for (int off = 1; off < SCAN_TB; off <<= 1) {
        int u = (t >= off) ? sh[t - off] : 0;
        __syncthreads();
        sh[t] += u;
        __syncthreads();
    }
    if (t < SCAN_NB) blockoff[t] = sh[t] - v;
    if (t == SCAN_NB - 1) rowptr[N_NODES] = sh[t];
}

__global__ void k_scanC(const u32* __restrict__ cnt, const int* __restrict__ thread_off,
                        const int* __restrict__ blockoff, int* __restrict__ rowptr) {
    int b = blockIdx.x, t = threadIdx.x;
    int base = b * SCAN_SEG + t * SCAN_EPT;
    int run = blockoff[b] + thread_off[b * SCAN_TB + t];
#pragma unroll
    for (int j = 0; j < SCAN_EPT; ++j) {
        int i = base + j;
        if (i < N_NODES) {
            rowptr[i] = run;
            run += padded_cnt(cnt, i);
        }
    }
}

// Atomic-free fill: epack[rowptr[r]+pos] = (col<<15) | (fp32bits(w)>>17).
// Pad slots stay 0 from the memset (col=0, w=+0.0 -> harmless hot-line gather).
__global__ void k_fill(const int* __restrict__ row, const int* __restrict__ col,
                       const float* __restrict__ w, const int* __restrict__ rowptr,
                       const unsigned char* __restrict__ pos_local,
                       u32* __restrict__ epack, int E) {
    int i = blockIdx.x * blockDim.x + threadIdx.x;
    if (i < E) {
        int pos = rowptr[row[i]] + (int)pos_local[i];
        epack[pos] = ((u32)col[i] << 15) | (__float_as_uint(w[i]) >> 17);
    }
}

// scale[n] = 0.9 / (sum of quantized w + 1e-10); zeros in pad slots add 0.
__global__ void k_scale(const int* __restrict__ rowptr, const u32* __restrict__ epack,
                        float* __restrict__ scale) {
    int n = blockIdx.x * blockDim.x + threadIdx.x;
    if (n >= N_NODES) return;
    int beg = rowptr[n], end = rowptr[n + 1];
    float s = 0.f;
    for (int e = beg; e < end; ++e)
        s += __uint_as_float((epack[e] & 0x7fffu) << 17);
    scale[n] = 0.9f / (s + 1e-10f);
}

// x (fp32, dense 48) -> fp16 rows padded to 128 B stride.
__global__ void k_x2h(const float4* __restrict__ x, float4* __restrict__ x16) {
    int i = blockIdx.x * blockDim.x + threadIdx.x;   // < N*6
    int n = i / TPN, c = i % TPN;
    if (n >= N_NODES) return;
    float4 a = x[n * 12 + 2 * c], b = x[n * 12 + 2 * c + 1];
    float4 o;
    ((__half2*)&o)[0] = __floats2half2_rn(a.x, a.y);
    ((__half2*)&o)[1] = __floats2half2_rn(a.z, a.w);
    ((__half2*)&o)[2] = __floats2half2_rn(b.x, b.y);
    ((__half2*)&o)[3] = __floats2half2_rn(b.z, b.w);
    x16[(n << 3) + c] = o;   // row stride 8 float4s (128 B)
}

// ---------------------------------------------------------------------------
// Pull: dst[n] = 0.1*x[n] + sum_e w*scale*h[col]. Rows multiple of 8 ->
// branchless unroll-8: 8 outstanding one-line 16 B gathers per lane.
#define GFMA(UJ, AA, BB)                                                      \
    {                                                                         \
        u32 uu = (UJ);                                                        \
        float4 hv = src16[((uu >> 15) << 3) + c];                             \
        float wv = __uint_as_float((uu & 0x7fffu) << 17) * sc;                \
        float2 f0 = __half22float2(*(__half2*)&hv.x);                         \
        float2 f1 = __half22float2(*(__half2*)&hv.y);                         \
        float2 f2 = __half22float2(*(__half2*)&hv.z);                         \
        float2 f3 = __half22float2(*(__half2*)&hv.w);                         \
        AA.x += wv * f0.x; AA.y += wv * f0.y; AA.z += wv * f1.x; AA.w += wv * f1.y; \
        BB.x += wv * f2.x; BB.y += wv * f2.y; BB.z += wv * f3.x; BB.w += wv * f3.y; \
    }

template <int LAST>
__global__ __launch_bounds__(192) void k_pull(const int* __restrict__ rowptr,
                                              const u32* __restrict__ epack,
                                              const float* __restrict__ scale,
                                              const float* __restrict__ x,
                                              const float4* __restrict__ src16,
                                              void* __restrict__ dstv) {
    int node = blockIdx.x * NPB + threadIdx.x / TPN;
    int c = threadIdx.x % TPN;
    if (node >= N_NODES) return;
    int beg = rowptr[node], end = rowptr[node + 1];
    float sc = scale[node];
    const f32x4* xp = (const f32x4*)(x + node * 48 + c * 8);
    f32x4 xa = __builtin_nontemporal_load(xp);
    f32x4 xb = __builtin_nontemporal_load(xp + 1);
    float4 A0 = make_float4(0.1f * xa.x, 0.1f * xa.y, 0.1f * xa.z, 0.1f * xa.w);
    float4 B0 = make_float4(0.1f * xb.x, 0.1f * xb.y, 0.1f * xb.z, 0.1f * xb.w);
    float4 A1 = make_float4(0, 0, 0, 0), B1 = make_float4(0, 0, 0, 0);
    float4 A2 = make_float4(0, 0, 0, 0), B2 = make_float4(0, 0, 0, 0);
    float4 A3 = make_float4(0, 0, 0, 0), B3 = make_float4(0, 0, 0, 0);
    for (int e = beg; e < end; e += 8) {
        const u32x4* ep = (const u32x4*)(epack + e);   // 32B-aligned (PAD=8)
        u32x4 pa = __builtin_nontemporal_load(ep);
        u32x4 pb = __builtin_nontemporal_load(ep + 1);
        GFMA(pa.x, A0, B0) GFMA(pa.y, A1, B1)
        GFMA(pa.z, A2, B2) GFMA(pa.w, A3, B3)
        GFMA(pb.x, A0, B0) GFMA(pb.y, A1, B1)
        GFMA(pb.z, A2, B2) GFMA(pb.w, A3, B3)
    }
    float4 RA = make_float4(A0.x + A1.x + A2.x + A3.x, A0.y + A1.y + A2.y + A3.y,
                            A0.z + A1.z + A2.z + A3.z, A0.w + A1.w + A2.w + A3.w);
    float4 RB = make_float4(B0.x + B1.x + B2.x + B3.x, B0.y + B1.y + B2.y + B3.y,
                            B0.z + B1.z + B2.z + B3.z, B0.w + B1.w + B2.w + B3.w);
    if (LAST) {
        float4* out = (float4*)dstv;
        out[node * 12 + 2 * c]     = RA;
        out[node * 12 + 2 * c + 1] = RB;
    } else {
        float4 o;
        ((__half2*)&o)[0] = __floats2half2_rn(RA.x, RA.y);
        ((__half2*)&o)[1] = __floats2half2_rn(RA.z, RA.w);
        ((__half2*)&o)[2] = __floats2half2_rn(RB.x, RB.y);
        ((__half2*)&o)[3] = __floats2half2_rn(RB.z, RB.w);
        ((float4*)dstv)[(node << 3) + c] = o;
    }
}

extern "C" void kernel_launch(void* const* d_in, const int* in_sizes, int n_in,
                              void* d_out, int out_size, void* d_ws, size_t ws_size,
                              hipStream_t stream) {
    const float* x  = (const float*)d_in[0];
    const int*   ei = (const int*)d_in[1];
    const float* w  = (const float*)d_in[2];
    const int E = in_sizes[2];
    const int* row = ei;        // destination (segment id)
    const int* col = ei + E;    // message source

    // Workspace (16B-aligned), total ~27.7 MB. hA16 (x16 + odd ping-pong
    // buffer) lives in d_out — dead before the final fp32 write.
    //   rowptr     @ 0           int[N+1]          -> 400,016
    //   epack      @ 400,016     u32[E+7N+16]      -> 9,600,096
    //   scale      @ 9,600,096   float[N]          -> 10,000,096
    //   thread_off @ 10,000,096  int[49*256]       -> 10,050,272
    //   blocksum   @ 10,050,272  int[256]          -> 10,051,296
    //   blockoff   @ 10,051,296  int[256]          -> 10,052,320
    //   cntS       @ 10,052,352  u32[N*8] (32B/row)-> 13,252,352
    //   pos_local  @ 13,252,352  u8[E]             -> 14,852,352
    //   hB16       @ 14,852,352  128B*N            -> 27,652,352
    char* ws = (char*)d_ws;
    int*           rowptr     = (int*)(ws);
    u32*           epack      = (u32*)(ws + 400016);
    float*         scale      = (float*)(ws + 9600096);
    int*           thread_off = (int*)(ws + 10000096);
    int*           blocksum   = (int*)(ws + 10050272);
    int*           blockoff   = (int*)(ws + 10051296);
    u32*           cntS       = (u32*)(ws + 10052352);
    unsigned char* pos_local  = (unsigned char*)(ws + 13252352);
    float4*        hB16       = (float4*)(ws + 14852352);
    float4*        hA16       = (float4*)d_out;      // x16 + odd ping-pong buffer

    const int B = 256;
    const int egrid = (E + B - 1) / B;
    const int ngrid = (N_NODES + B - 1) / B;
    const int pgrid = N_NODES / NPB;                 // 3125, exact
    const int xgrid = (N_NODES * TPN + 191) / 192;

    hipMemsetAsync(cntS, 0, (size_t)N_NODES * CSTRIDE * sizeof(u32), stream);
    hipMemsetAsync(epack, 0, (size_t)(N_EDGES + 7 * N_NODES + 16) * sizeof(u32), stream);
    k_count<<<egrid, B, 0, stream>>>(row, cntS, pos_local, E);
    k_scanA<<<SCAN_NB, SCAN_TB, 0, stream>>>(cntS, thread_off, blocksum);
    k_scanB<<<1, SCAN_TB, 0, stream>>>(blocksum, blockoff, rowptr);
    k_scanC<<<SCAN_NB, SCAN_TB, 0, stream>>>(cntS, thread_off, blockoff, rowptr);
    k_fill <<<egrid, B, 0, stream>>>(row, col, w, rowptr, pos_local, epack, E);
    k_scale<<<ngrid, B, 0, stream>>>(rowptr, epack, scale);
    k_x2h  <<<xgrid, 192, 0, stream>>>((const float4*)x, hA16);

    // p1: A->B, p2: B->A, ..., p9: A->B (9 fp16 pulls); p10: B -> d_out fp32
    float4* src = hA16;
    float4* dst = hB16;
    for (int k = 1; k <= K_ITER - 1; ++k) {
        k_pull<0><<<pgrid, NPB * TPN, 0, stream>>>(rowptr, epack, scale,
                                                   x, src, dst);
        float4* t = src; src = dst; dst = t;
    }
    k_pull<1><<<pgrid, NPB * TPN, 0, stream>>>(rowptr, epack, scale,
                                               x, src, d_out);
}

// Round 11
// 493.299 us; speedup vs baseline: 1.0721x; 1.0721x over previous
//
#include <hip/hip_runtime.h>
#include <hip/hip_fp16.h>

#define N_NODES 100000
#define N_EDGES 1600000
#define K_ITER 10

#define TPN 6     // threads per node; lane owns 8 feats (16 B fp16 gather)
#define NPB 32    // nodes per block (192 threads = 3 waves)
#define PAD 4     // row length padded to multiple of 4 (zero-edges)
#define CSTRIDE 8 // counter spread: one u32 per 32 B sector

#define SCAN_TB   256
#define SCAN_EPT  8
#define SCAN_SEG  (SCAN_TB * SCAN_EPT)
#define SCAN_NB   ((N_NODES + SCAN_SEG - 1) / SCAN_SEG)   // 49

typedef unsigned int u32;

// ---------------------------------------------------------------------------
// Spread counters: cnt[r*8] — one counter per 32 B sector.
__global__ void k_count(const int* __restrict__ row, u32* __restrict__ cnt,
                        unsigned char* __restrict__ pos_local, int E) {
    int i = blockIdx.x * blockDim.x + threadIdx.x;
    if (i < E) pos_local[i] = (unsigned char)atomicAdd(&cnt[row[i] << 3], 1u);
}

__device__ __forceinline__ int padded_cnt(const u32* cnt, int i) {
    int cv = (int)cnt[i << 3];
    return (cv + (PAD - 1)) & ~(PAD - 1);
}

__global__ void k_scanA(const u32* __restrict__ cnt, int* __restrict__ thread_off,
                        int* __restrict__ blocksum) {
    __shared__ int sh[SCAN_TB];
    int b = blockIdx.x, t = threadIdx.x;
    int base = b * SCAN_SEG + t * SCAN_EPT;
    int s = 0;
#pragma unroll
    for (int j = 0; j < SCAN_EPT; ++j) {
        int i = base + j;
        if (i < N_NODES) s += padded_cnt(cnt, i);
    }
    sh[t] = s;
    __syncthreads();
    for (int off = 1; off < SCAN_TB; off <<= 1) {
        int v = (t >= off) ? sh[t - off] : 0;
        __syncthreads();
        sh[t] += v;
        __syncthreads();
    }
    thread_off[b * SCAN_TB + t] = sh[t] - s;
    if (t == SCAN_TB - 1) blocksum[b] = sh[t];
}

__global__ void k_scanB(const int* __restrict__ blocksum, int* __restrict__ blockoff,
                        int* __restrict__ rowptr) {
    __shared__ int sh[SCAN_TB];
    int t = threadIdx.x;
    int v = (t < SCAN_NB) ? blocksum[t] : 0;
    sh[t] = v;
    __syncthreads();
    for (int off = 1; off < SCAN_TB; off <<= 1) {
        int u = (t >= off) ? sh[t - off] : 0;
        __syncthreads();
        sh[t] += u;
        __syncthreads();
    }
    if (t < SCAN_NB) blockoff[t] = sh[t] - v;
    if (t == SCAN_NB - 1) rowptr[N_NODES] = sh[t];
}

__global__ void k_scanC(const u32* __restrict__ cnt, const int* __restrict__ thread_off,
                        const int* __restrict__ blockoff, int* __restrict__ rowptr) {
    int b = blockIdx.x, t = threadIdx.x;
    int base = b * SCAN_SEG + t * SCAN_EPT;
    int run = blockoff[b] + thread_off[b * SCAN_TB + t];
#pragma unroll
    for (int j = 0; j < SCAN_EPT; ++j) {
        int i = base + j;
        if (i < N_NODES) {
            rowptr[i] = run;
            run += padded_cnt(cnt, i);
        }
    }
}

// Atomic-free fill: epack[rowptr[r]+pos] = (col<<15) | (fp32bits(w)>>17).
__global__ void k_fill(const int* __restrict__ row, const int* __restrict__ col,
                       const float* __restrict__ w, const int* __restrict__ rowptr,
                       const unsigned char* __restrict__ pos_local,
                       u32* __restrict__ epack, int E) {
    int i = blockIdx.x * blockDim.x + threadIdx.x;
    if (i < E) {
        int pos = rowptr[row[i]] + (int)pos_local[i];
        epack[pos] = ((u32)col[i] << 15) | (__float_as_uint(w[i]) >> 17);
    }
}

// scale[n] = 0.9 / (sum of quantized w + 1e-10); zeros in pad slots add 0.
__global__ void k_scale(const int* __restrict__ rowptr, const u32* __restrict__ epack,
                        float* __restrict__ scale) {
    int n = blockIdx.x * blockDim.x + threadIdx.x;
    if (n >= N_NODES) return;
    int beg = rowptr[n], end = rowptr[n + 1];
    float s = 0.f;
    for (int e = beg; e < end; ++e)
        s += __uint_as_float((epack[e] & 0x7fffu) << 17);
    scale[n] = 0.9f / (s + 1e-10f);
}

// x (fp32, dense 48) -> fp16 rows padded to 128 B stride.
__global__ void k_x2h(const float4* __restrict__ x, float4* __restrict__ x16) {
    int i = blockIdx.x * blockDim.x + threadIdx.x;   // < N*6
    int n = i / TPN, c = i % TPN;
    if (n >= N_NODES) return;
    float4 a = x[n * 12 + 2 * c], b = x[n * 12 + 2 * c + 1];
    float4 o;
    ((__half2*)&o)[0] = __floats2half2_rn(a.x, a.y);
    ((__half2*)&o)[1] = __floats2half2_rn(a.z, a.w);
    ((__half2*)&o)[2] = __floats2half2_rn(b.x, b.y);
    ((__half2*)&o)[3] = __floats2half2_rn(b.z, b.w);
    x16[(n << 3) + c] = o;   // row stride 8 float4s (128 B)
}

// ---------------------------------------------------------------------------
// Pull with 2-stage software pipeline: batch j+1's epack + gathers are issued
// before batch j's FMAs consume, overlapping gather latency with VALU.
#define PFMA(UU, HV, AA, BB)                                                  \
    {                                                                         \
        float wv = __uint_as_float(((UU) & 0x7fffu) << 17) * sc;              \
        float2 f0 = __half22float2(*(__half2*)&HV.x);                         \
        float2 f1 = __half22float2(*(__half2*)&HV.y);                         \
        float2 f2 = __half22float2(*(__half2*)&HV.z);                         \
        float2 f3 = __half22float2(*(__half2*)&HV.w);                         \
        AA.x += wv * f0.x; AA.y += wv * f0.y; AA.z += wv * f1.x; AA.w += wv * f1.y; \
        BB.x += wv * f2.x; BB.y += wv * f2.y; BB.z += wv * f3.x; BB.w += wv * f3.y; \
    }

template <int LAST>
__global__ __launch_bounds__(192) void k_pull(const int* __restrict__ rowptr,
                                              const u32* __restrict__ epack,
                                              const float* __restrict__ scale,
                                              const float4* __restrict__ x,
                                              const float4* __restrict__ src16,
                                              void* __restrict__ dstv) {
    int node = blockIdx.x * NPB + threadIdx.x / TPN;
    int c = threadIdx.x % TPN;
    if (node >= N_NODES) return;
    int beg = rowptr[node], end = rowptr[node + 1];
    float sc = scale[node];
    float4 xa = x[node * 12 + 2 * c], xb = x[node * 12 + 2 * c + 1];
    float4 A0 = make_float4(0.1f * xa.x, 0.1f * xa.y, 0.1f * xa.z, 0.1f * xa.w);
    float4 B0 = make_float4(0.1f * xb.x, 0.1f * xb.y, 0.1f * xb.z, 0.1f * xb.w);
    float4 A1 = make_float4(0, 0, 0, 0), B1 = make_float4(0, 0, 0, 0);
    if (beg < end) {
        uint4 p = *(const uint4*)(epack + beg);
        float4 h0 = src16[((p.x >> 15) << 3) + c];
        float4 h1 = src16[((p.y >> 15) << 3) + c];
        float4 h2 = src16[((p.z >> 15) << 3) + c];
        float4 h3 = src16[((p.w >> 15) << 3) + c];
        for (int e = beg + 4; e < end; e += 4) {
            uint4 pn = *(const uint4*)(epack + e);       // next batch: issue first
            float4 g0 = src16[((pn.x >> 15) << 3) + c];
            float4 g1 = src16[((pn.y >> 15) << 3) + c];
            float4 g2 = src16[((pn.z >> 15) << 3) + c];
            float4 g3 = src16[((pn.w >> 15) << 3) + c];
            PFMA(p.x, h0, A0, B0) PFMA(p.y, h1, A1, B1)  // consume current
            PFMA(p.z, h2, A0, B0) PFMA(p.w, h3, A1, B1)
            p = pn; h0 = g0; h1 = g1; h2 = g2; h3 = g3;
        }
        PFMA(p.x, h0, A0, B0) PFMA(p.y, h1, A1, B1)
        PFMA(p.z, h2, A0, B0) PFMA(p.w, h3, A1, B1)
    }
    float4 RA = make_float4(A0.x + A1.x, A0.y + A1.y, A0.z + A1.z, A0.w + A1.w);
    float4 RB = make_float4(B0.x + B1.x, B0.y + B1.y, B0.z + B1.z, B0.w + B1.w);
    if (LAST) {
        float4* out = (float4*)dstv;
        out[node * 12 + 2 * c]     = RA;
        out[node * 12 + 2 * c + 1] = RB;
    } else {
        float4 o;
        ((__half2*)&o)[0] = __floats2half2_rn(RA.x, RA.y);
        ((__half2*)&o)[1] = __floats2half2_rn(RA.z, RA.w);
        ((__half2*)&o)[2] = __floats2half2_rn(RB.x, RB.y);
        ((__half2*)&o)[3] = __floats2half2_rn(RB.z, RB.w);
        ((float4*)dstv)[(node << 3) + c] = o;
    }
}

extern "C" void kernel_launch(void* const* d_in, const int* in_sizes, int n_in,
                              void* d_out, int out_size, void* d_ws, size_t ws_size,
                              hipStream_t stream) {
    const float* x  = (const float*)d_in[0];
    const int*   ei = (const int*)d_in[1];
    const float* w  = (const float*)d_in[2];
    const int E = in_sizes[2];
    const int* row = ei;        // destination (segment id)
    const int* col = ei + E;    // message source

    // Workspace (16B-aligned), total ~27.7 MB. hA16 (x16 + odd ping-pong
    // buffer) lives in d_out — dead before the final fp32 write.
    //   rowptr     @ 0           int[N+1]          -> 400,016
    //   epack      @ 400,016     u32[E+3N+16]      -> 9,600,096 region (slack)
    //   scale      @ 9,600,096   float[N]          -> 10,000,096
    //   thread_off @ 10,000,096  int[49*256]       -> 10,050,272
    //   blocksum   @ 10,050,272  int[256]          -> 10,051,296
    //   blockoff   @ 10,051,296  int[256]          -> 10,052,320
    //   cntS       @ 10,052,352  u32[N*8] (32B/row)-> 13,252,352
    //   pos_local  @ 13,252,352  u8[E]             -> 14,852,352
    //   hB16       @ 14,852,352  128B*N            -> 27,652,352
    char* ws = (char*)d_ws;
    int*           rowptr     = (int*)(ws);
    u32*           epack      = (u32*)(ws + 400016);
    float*         scale      = (float*)(ws + 9600096);
    int*           thread_off = (int*)(ws + 10000096);
    int*           blocksum   = (int*)(ws + 10050272);
    int*           blockoff   = (int*)(ws + 10051296);
    u32*           cntS       = (u32*)(ws + 10052352);
    unsigned char* pos_local  = (unsigned char*)(ws + 13252352);
    float4*        hB16       = (float4*)(ws + 14852352);
    float4*        hA16       = (float4*)d_out;      // x16 + odd ping-pong buffer

    const int B = 256;
    const int egrid = (E + B - 1) / B;
    const int ngrid = (N_NODES + B - 1) / B;
    const int pgrid = N_NODES / NPB;                 // 3125, exact
    const int xgrid = (N_NODES * TPN + 191) / 192;

    hipMemsetAsync(cntS, 0, (size_t)N_NODES * CSTRIDE * sizeof(u32), stream);
    hipMemsetAsync(epack, 0, (size_t)(N_EDGES + 3 * N_NODES + 16) * sizeof(u32), stream);
    k_count<<<egrid, B, 0, stream>>>(row, cntS, pos_local, E);
    k_scanA<<<SCAN_NB, SCAN_TB, 0, stream>>>(cntS, thread_off, blocksum);
    k_scanB<<<1, SCAN_TB, 0, stream>>>(blocksum, blockoff, rowptr);
    k_scanC<<<SCAN_NB, SCAN_TB, 0, stream>>>(cntS, thread_off, blockoff, rowptr);
    k_fill <<<egrid, B, 0, stream>>>(row, col, w, rowptr, pos_local, epack, E);
    k_scale<<<ngrid, B, 0, stream>>>(rowptr, epack, scale);
    k_x2h  <<<xgrid, 192, 0, stream>>>((const float4*)x, hA16);

    // p1: A->B, p2: B->A, ..., p9: A->B (9 fp16 pulls); p10: B -> d_out fp32
    float4* src = hA16;
    float4* dst = hB16;
    for (int k = 1; k <= K_ITER - 1; ++k) {
        k_pull<0><<<pgrid, NPB * TPN, 0, stream>>>(rowptr, epack, scale,
                                                   (const float4*)x, src, dst);
        float4* t = src; src = dst; dst = t;
    }
    k_pull<1><<<pgrid, NPB * TPN, 0, stream>>>(rowptr, epack, scale,
                                               (const float4*)x, src, d_out);
}